// Round 19
// baseline (65.688 us; speedup 1.0000x reference)
//
#include <hip/hip_runtime.h>
#include <hip/hip_bf16.h>

// Problem constants
#define L_SEQ   4096
#define D_IN    1024
#define N_BATCH 16
#define L_OUT   1024
#define D_OUT   1024
#define M_DIM   (N_BATCH * L_OUT)   // 16384
#define K_DIM   D_IN

// GEMM tiling: 256x256, BK=32, fp32-A direct-from-x, B direct-from-L2 regs
#define BM 256
#define BN 256
#define BK 32
#define NKT (K_DIM / BK)   // 32

typedef __attribute__((ext_vector_type(4))) float  f32x4;
typedef __attribute__((ext_vector_type(8))) __bf16 bf16x8;
typedef __attribute__((ext_vector_type(4))) __bf16 bf16x4;

// ws layout (bytes): W fragment-major bf16 (2 MiB) + s_arr
#define WS_W_OFF 0u
#define WS_S_OFF (4u * 1024u * 1024u)

// ---------------------------------------------------------------------------
// Kernel 1 (prep): blocks 0..15 -> mask sums; blocks 16..1039 -> W rows into
// FRAGMENT-MAJOR layout: 16B unit index
//   idx16 = ((tile_n*2+wn)*32 + kt)*512 + f*64 + (g4*16+fr)
// holds B[n][kt*32+g4*8 .. +8] for n = tile_n*256+wn*128+f*16+fr.
// GEMM waves then read B fragments as fully-coalesced 1KB global loads.
// ---------------------------------------------------------------------------
__global__ __launch_bounds__(256) void prep_kernel(
    const int*   __restrict__ mask,  // (16, 4096)
    const float* __restrict__ W,     // (1024, 1024)
    int*    __restrict__ s_out,      // (16,)
    __bf16* __restrict__ wsW2)       // (1M elems) fragment-major
{
    const int t = threadIdx.x;
    if (blockIdx.x < 16) {
        const int b = blockIdx.x;
        const int* row = mask + (size_t)b * L_SEQ;
        int sum = 0;
#pragma unroll
        for (int i = 0; i < L_SEQ / 256; ++i) sum += row[t + i * 256];
#pragma unroll
        for (int off = 32; off > 0; off >>= 1) sum += __shfl_down(sum, off, 64);
        __shared__ int wsum[4];
        if ((t & 63) == 0) wsum[t >> 6] = sum;
        __syncthreads();
        if (t == 0) {
            int total = wsum[0] + wsum[1] + wsum[2] + wsum[3];
            s_out[b] = total < L_OUT ? total : L_OUT;
        }
    } else {
        const int n  = blockIdx.x - 16;          // 0..1023 (W row = out col)
        const int k0 = t * 4;                    // 4 consecutive k
        const int kt  = k0 >> 5;                 // 0..31
        const int g4p = (k0 >> 3) & 3;           // 0..3
        const int e   = k0 & 7;                  // 0 or 4
        const int tn  = n >> 8;
        const int wnp = (n >> 7) & 1;
        const int f   = (n >> 4) & 7;
        const int fr  = n & 15;
        const size_t idx16 =
            ((size_t)((tn * 2 + wnp) * 32 + kt)) * 512 + f * 64 + g4p * 16 + fr;
        f32x4 v = *(const f32x4*)(W + (size_t)n * D_IN + k0);
        bf16x4 o = {(__bf16)v.x, (__bf16)v.y, (__bf16)v.z, (__bf16)v.w};
        *(bf16x4*)((char*)wsW2 + idx16 * 16 + e * 2) = o;
    }
}

// ---------------------------------------------------------------------------
// Kernel 2: fused GEMM. A staged fp32 from x via global_load_lds (R17 path,
// unchanged: XOR-swizzled source, linear dest, triple buffer). B read
// DIRECTLY from L2-resident fragment-major ws2 into double-buffered regs —
// B never touches LDS. LDS/kt: 96 KB (was 176) — the diagnosed bottleneck.
// vmcnt ledger (in-order): P1(kt) issues B(kt+1)8 regs; P2(kt) stages
// A(kt+2)4. Queue at P1(kt): [A(kt)4][B(kt)8][A(kt+1)4] -> vmcnt(12)
// retires A(kt); compiler auto-waits the B regs before MFMA. Last kt: 0.
// WRITE-SAFETY: A(kt+2)->a2 at P2, last read P1(kt-1) (>=1 barrier back);
// B has no LDS writes. (R15 lesson holds.)
// ---------------------------------------------------------------------------
__device__ __forceinline__ void gload16v(const void* g, void* l) {
    __builtin_amdgcn_global_load_lds(
        (const __attribute__((address_space(1))) void*)g,
        (__attribute__((address_space(3))) void*)l,
        16, 0, 0);
}

#define FENCE() asm volatile("" ::: "memory")

__global__ __launch_bounds__(512, 2) void gemm_kernel(
    const float*  __restrict__ x,    // (16, 4096, 1024) fp32
    const __bf16* __restrict__ Wb2,  // fragment-major bf16 (2 MiB)
    const float*  __restrict__ bias, // (1024,)
    const int*    __restrict__ s_arr,// (16,)
    float* __restrict__ out)         // (16384, 1024)
{
    __shared__ float sAf[3][BM * BK];    // 96 KiB (fp32 A, triple buffer)

    const int t  = threadIdx.x;       // 0..511
    const int bx = blockIdx.x;        // 256 blocks
    const int vb = (bx & 7) * 32 + (bx >> 3);  // T1 XCD-grouping swizzle
    const int tile_n = vb & 3;
    const int tile_m = vb >> 2;
    const int m0 = tile_m * BM;
    const int n0 = tile_n * BN;
    const int lane = t & 63;
    const int wave = t >> 6;
    const int wm = wave & 3;          // 0..3 (64 rows each)
    const int wn = wave >> 2;         // 0..1 (128 cols each)

    // ---- A staging geometry (4 rounds x 64 rows x 32 f32) ----
    const int bb = m0 >> 10;
    const int s  = s_arr[bb];
    const int jb = m0 & (L_OUT - 1);
    const float* xb = x + (size_t)bb * L_SEQ * D_IN;
    const int ascol = (((t & 7) ^ ((t >> 3) & 7)) * 4);   // swizzled SOURCE col
    const float* asrc[4];
    int  adst[4];
    int  arow[4];
#pragma unroll
    for (int r = 0; r < 4; ++r) {
        const int rr = 64 * r + (t >> 3);        // row in tile 0..255
        const int j  = jb + rr;
        const int xr = (j < s) ? (L_SEQ - s + j) : 0;  // clamped-safe
        asrc[r] = xb + (size_t)xr * D_IN + ascol;
        adst[r] = rr * BK + (t & 7) * 4;         // linear dest (f32 elems)
        arow[r] = j;
    }
#define STAGE_A(abuf, kt_)                                                 \
    {                                                                      \
        _Pragma("unroll")                                                  \
        for (int r = 0; r < 4; ++r)                                        \
            gload16v(asrc[r] + (kt_) * BK, (abuf) + adst[r]);              \
    }

    // ---- B direct-from-L2 (fragment-major): per wave, 8 coalesced 16B/lane
    const bf16x8* bgw = (const bf16x8*)Wb2 +
        (size_t)(tile_n * 2 + wn) * 32 * 512 + lane;
#define LOAD_BREG(BB, kt_)                                                 \
    {                                                                      \
        _Pragma("unroll")                                                  \
        for (int f = 0; f < 8; ++f)                                        \
            BB[f] = bgw[(kt_) * 512 + f * 64];                             \
    }

    // ---- fragment read geometry ----
    const int fr = lane & 15;
    const int g4 = lane >> 4;         // 0..3 (k-group)

    float bias_v[8];
#pragma unroll
    for (int q = 0; q < 8; ++q)
        bias_v[q] = bias[n0 + wn * 128 + q * 16 + fr];

    bf16x8 aF[4], bBa[8], bBb[8];
    f32x4 acc[4][8];
#pragma unroll
    for (int i = 0; i < 4; ++i)
#pragma unroll
        for (int q = 0; q < 8; ++q) acc[i][q] = (f32x4){0.f, 0.f, 0.f, 0.f};

    // A frag: R = wm*64 + i*16 + fr; slots (2g4, 2g4+1) ^ (R&7)
#define LOAD_A32(abuf)                                                     \
    {                                                                      \
        _Pragma("unroll")                                                  \
        for (int i = 0; i < 4; ++i) {                                      \
            const int R_ = wm * 64 + i * 16 + fr;                          \
            const float* rbase_ = (abuf) + R_ * BK;                        \
            f32x4 lo_ = *(const f32x4*)&rbase_[((2*g4)   ^ (R_ & 7)) * 4]; \
            f32x4 hi_ = *(const f32x4*)&rbase_[((2*g4+1) ^ (R_ & 7)) * 4]; \
            aF[i] = (bf16x8){(__bf16)lo_.x, (__bf16)lo_.y, (__bf16)lo_.z,  \
                             (__bf16)lo_.w, (__bf16)hi_.x, (__bf16)hi_.y,  \
                             (__bf16)hi_.z, (__bf16)hi_.w};                \
        }                                                                  \
    }

#define MFMA16LO(BB)                                                       \
    {                                                                      \
        _Pragma("unroll")                                                  \
        for (int i = 0; i < 4; ++i)                                        \
            _Pragma("unroll")                                              \
            for (int j = 0; j < 4; ++j)                                    \
                acc[i][j] = __builtin_amdgcn_mfma_f32_16x16x32_bf16(       \
                    aF[i], BB[j], acc[i][j], 0, 0, 0);                     \
    }
#define MFMA16HI(BB)                                                       \
    {                                                                      \
        _Pragma("unroll")                                                  \
        for (int i = 0; i < 4; ++i)                                        \
            _Pragma("unroll")                                              \
            for (int j = 0; j < 4; ++j)                                    \
                acc[i][4 + j] = __builtin_amdgcn_mfma_f32_16x16x32_bf16(   \
                    aF[i], BB[4 + j], acc[i][4 + j], 0, 0, 0);             \
    }

    // rotating A buffers
    float* a0 = &sAf[0][0];
    float* a1 = &sAf[1][0];
    float* a2 = &sAf[2][0];

    // ---- prologue: A(0)[4], B(0)[8 regs], A(1)[4] ----
    STAGE_A(a0, 0);
    LOAD_BREG(bBa, 0);
    STAGE_A(a1, 1);

#define BODY(KT, BBc, BBn)                                                 \
    {                                                                      \
        FENCE();                                                           \
        if ((KT) == NKT - 1)                                               \
            asm volatile("s_waitcnt vmcnt(0)" ::: "memory");               \
        else                                                               \
            asm volatile("s_waitcnt vmcnt(12)" ::: "memory");              \
        __builtin_amdgcn_s_barrier();                                      \
        FENCE();                                                           \
        if (s < L_OUT) {                                                   \
            _Pragma("unroll")                                              \
            for (int r = 0; r < 4; ++r)                                    \
                if (arow[r] >= s)                                          \
                    *(f32x4*)&a0[adst[r]] = (f32x4){0.f, 0.f, 0.f, 0.f};   \
            __syncthreads();                                               \
        }                                                                  \
        LOAD_A32(a0);                                                      \
        if ((KT) + 1 < NKT) LOAD_BREG(BBn, (KT) + 1);                      \
        __builtin_amdgcn_s_setprio(1);                                     \
        MFMA16LO(BBc);                                                     \
        __builtin_amdgcn_s_setprio(0);                                     \
        FENCE();                                                           \
        __builtin_amdgcn_s_barrier();                                      \
        FENCE();                                                           \
        if ((KT) + 2 < NKT) STAGE_A(a2, (KT) + 2);                         \
        __builtin_amdgcn_s_setprio(1);                                     \
        MFMA16HI(BBc);                                                     \
        __builtin_amdgcn_s_setprio(0);                                     \
        { float* ta = a0; a0 = a1; a1 = a2; a2 = ta; }                     \
    }

    for (int kt = 0; kt < NKT; kt += 2) {
        BODY(kt,     bBa, bBb);
        BODY(kt + 1, bBb, bBa);
    }

    // ---- epilogue: bias + store ----
    const int row0 = m0 + wm * 64 + (lane >> 4) * 4;
    const int col0 = n0 + wn * 128 + fr;
#pragma unroll
    for (int i = 0; i < 4; ++i)
#pragma unroll
        for (int q = 0; q < 8; ++q)
#pragma unroll
            for (int rr = 0; rr < 4; ++rr)
                out[(size_t)(row0 + i * 16 + rr) * D_OUT + (col0 + q * 16)] =
                    acc[i][q][rr] + bias_v[q];

#undef STAGE_A
#undef LOAD_BREG
#undef LOAD_A32
#undef MFMA16LO
#undef MFMA16HI
#undef BODY
}

// ---------------------------------------------------------------------------
extern "C" void kernel_launch(void* const* d_in, const int* in_sizes, int n_in,
                              void* d_out, int out_size, void* d_ws, size_t ws_size,
                              hipStream_t stream) {
    const float* x    = (const float*)d_in[0];
    const int*   mask = (const int*)d_in[1];
    const float* W    = (const float*)d_in[2];
    const float* bias = (const float*)d_in[3];
    float*       out  = (float*)d_out;

    __bf16* wsW2  = (__bf16*)((char*)d_ws + WS_W_OFF);
    int*    s_arr = (int*)((char*)d_ws + WS_S_OFF);

    prep_kernel<<<dim3(16 + D_OUT), dim3(256), 0, stream>>>(
        mask, W, s_arr, wsW2);

    const int grid = (M_DIM / BM) * (D_OUT / BN);  // 64 * 4 = 256
    gemm_kernel<<<dim3(grid), dim3(512), 0, stream>>>(
        x, wsW2, bias, s_arr, out);
}

// Round 20
// 51.720 us; speedup vs baseline: 1.2701x; 1.2701x over previous
//
#include <hip/hip_runtime.h>
#include <hip/hip_bf16.h>

// Problem constants
#define L_SEQ   4096
#define D_IN    1024
#define N_BATCH 16
#define L_OUT   1024
#define D_OUT   1024
#define M_DIM   (N_BATCH * L_OUT)   // 16384
#define K_DIM   D_IN

// GEMM tiling: 128x256, BK=32, fp32-A direct-from-x, 2 blocks/CU
#define BM 128
#define BN 256
#define BK 32
#define NKT (K_DIM / BK)   // 32

typedef __attribute__((ext_vector_type(4))) float  f32x4;
typedef __attribute__((ext_vector_type(8))) __bf16 bf16x8;
typedef __attribute__((ext_vector_type(4))) __bf16 bf16x4;

// ws layout (bytes): W bf16 (2 MiB) + s_arr
#define WS_W_OFF 0u
#define WS_S_OFF (4u * 1024u * 1024u)

// ---------------------------------------------------------------------------
// Kernel 1 (prep): blocks 0..15 -> mask sums; blocks 16..1039 -> W rows.
// W swizzle (32-elem groups): 8-elem slot sl -> sl ^ ((row>>1)&3).
// ---------------------------------------------------------------------------
__global__ __launch_bounds__(256) void prep_kernel(
    const int*   __restrict__ mask,  // (16, 4096)
    const float* __restrict__ W,     // (1024, 1024)
    int*    __restrict__ s_out,      // (16,)
    __bf16* __restrict__ wsW)        // (1024, 1024) swizzled
{
    const int t = threadIdx.x;
    if (blockIdx.x < 16) {
        const int b = blockIdx.x;
        const int* row = mask + (size_t)b * L_SEQ;
        int sum = 0;
#pragma unroll
        for (int i = 0; i < L_SEQ / 256; ++i) sum += row[t + i * 256];
#pragma unroll
        for (int off = 32; off > 0; off >>= 1) sum += __shfl_down(sum, off, 64);
        __shared__ int wsum[4];
        if ((t & 63) == 0) wsum[t >> 6] = sum;
        __syncthreads();
        if (t == 0) {
            int total = wsum[0] + wsum[1] + wsum[2] + wsum[3];
            s_out[b] = total < L_OUT ? total : L_OUT;
        }
    } else {
        const int n  = blockIdx.x - 16;          // 0..1023
        const int e0 = t * 4;
        const int sl   = (e0 >> 3) & 3;
        const int dste = (e0 & ~31) | ((sl ^ ((n >> 1) & 3)) << 3) | (e0 & 7);
        const float* src = W + (size_t)n * D_IN + e0;
        f32x4 v = *(const f32x4*)src;
        bf16x4 o = {(__bf16)v.x, (__bf16)v.y, (__bf16)v.z, (__bf16)v.w};
        *(bf16x4*)(wsW + (size_t)n * K_DIM + dste) = o;
    }
}

// ---------------------------------------------------------------------------
// Kernel 2: fused GEMM, A staged fp32 DIRECTLY from x via global_load_lds.
// CHANGE vs R17: BM 256->128, threads 512->256 (4 waves 2Mx2N, wave tile
// 64x128 UNCHANGED), LDS 80 KiB -> 2 blocks/CU. Two independent barrier
// domains per CU: one block's MFMA covers the other's LDS read-burst
// (breaks the lockstep serial LDS+MFMA sum diagnosed at R17 = 3500 cyc/kt
// vs 1400 floor; m114 co-scheduling). x-redundancy stays 4x (BN=256) —
// R18's failure cause (BN=128 -> 8x) avoided.
// vmcnt ledger (in-order): prologue A(0)4,B(0)4,A(1)4; P1(kt) issues
// B(kt+1)4; P2(kt) stages A(kt+2)4. Queue at P1(kt): [B(kt)4][A(kt+1)4]
// -> steady vmcnt(4) retires B(kt)+older, leaves A(kt+1). Last kt: 0.
// WRITE-SAFETY (R15 lesson): B(kt+1)->nxt at P1(kt), nxt last read
// P2(kt-1), P1(kt) barrier separates; A(kt+2)->a2 at P2(kt), a2 last read
// P1(kt-1), >=2 barriers back. No same-phase overwrite of any read set.
// ---------------------------------------------------------------------------
__device__ __forceinline__ void gload16v(const void* g, void* l) {
    __builtin_amdgcn_global_load_lds(
        (const __attribute__((address_space(1))) void*)g,
        (__attribute__((address_space(3))) void*)l,
        16, 0, 0);
}

#define FENCE() asm volatile("" ::: "memory")

__global__ __launch_bounds__(256, 2) void gemm_kernel(
    const float*  __restrict__ x,    // (16, 4096, 1024) fp32
    const __bf16* __restrict__ Wb,   // (1024, 1024) swizzled bf16
    const float*  __restrict__ bias, // (1024,)
    const int*    __restrict__ s_arr,// (16,)
    float* __restrict__ out)         // (16384, 1024)
{
    __shared__ float  sAf[3][BM * BK];   // 48 KiB (fp32 A, triple buffer)
    __shared__ __bf16 sB [2][BN * BK];   // 32 KiB (bf16 B, double buffer)

    const int t  = threadIdx.x;       // 0..255
    const int bx = blockIdx.x;        // 512 blocks
    const int vb = (bx & 7) * 64 + (bx >> 3);  // T1: tile_m sharers on 1 XCD
    const int tile_n = vb & 3;        // N/BN = 4
    const int tile_m = vb >> 2;       // M/BM = 128
    const int m0 = tile_m * BM;
    const int n0 = tile_n * BN;
    const int lane = t & 63;
    const int wave = t >> 6;          // 0..3
    const int wm = wave & 1;          // 2M (64 rows each)
    const int wn = wave >> 1;         // 2N (128 cols each)

    // ---- A staging geometry (4 rounds x 32 rows x 32 f32) ----
    const int bb = m0 >> 10;
    const int s  = s_arr[bb];
    const int jb = m0 & (L_OUT - 1);
    const float* xb = x + (size_t)bb * L_SEQ * D_IN;
    const int ascol = (((t & 7) ^ ((t >> 3) & 7)) * 4);   // swizzled SOURCE col
    const float* asrc[4];
    int  adst[4];
    int  arow[4];
#pragma unroll
    for (int r = 0; r < 4; ++r) {
        const int rr = 32 * r + (t >> 3);        // row in tile 0..127
        const int j  = jb + rr;
        const int xr = (j < s) ? (L_SEQ - s + j) : 0;  // clamped-safe
        asrc[r] = xb + (size_t)xr * D_IN + ascol;
        adst[r] = rr * BK + (t & 7) * 4;         // linear dest (f32 elems)
        arow[r] = j;
    }
#define STAGE_A(abuf, kt_)                                                 \
    {                                                                      \
        _Pragma("unroll")                                                  \
        for (int r = 0; r < 4; ++r)                                        \
            gload16v(asrc[r] + (kt_) * BK, (abuf) + adst[r]);              \
    }

    // ---- B staging geometry (4 rounds x 64 rows x 32 bf16) ----
    const __bf16* Bg = Wb + (size_t)n0 * K_DIM;
    const int brow = t >> 2;          // 0..63
    const int bcol = (t & 3) * 8;     // elem col (linear; content swizzled)
#define STAGE_B(buf, kt_)                                                  \
    {                                                                      \
        _Pragma("unroll")                                                  \
        for (int r = 0; r < 4; ++r) {                                      \
            const int row_ = 64 * r + brow;                                \
            gload16v(Bg + (size_t)row_ * K_DIM + (kt_) * BK + bcol,        \
                     &sB[buf][row_ * BK + bcol]);                          \
        }                                                                  \
    }

    // ---- fragment read geometry ----
    const int fr = lane & 15;
    const int g4 = lane >> 4;         // 0..3 (k-group)

    float bias_v[8];
#pragma unroll
    for (int q = 0; q < 8; ++q)
        bias_v[q] = bias[n0 + wn * 128 + q * 16 + fr];

    bf16x8 aF[4], bBlo[4], bBhi[4];
    f32x4 acc[4][8];
#pragma unroll
    for (int i = 0; i < 4; ++i)
#pragma unroll
        for (int q = 0; q < 8; ++q) acc[i][q] = (f32x4){0.f, 0.f, 0.f, 0.f};

    // A frag: R = wm*64 + i*16 + fr; slots (2g4, 2g4+1) ^ (R&7)
#define LOAD_A32(abuf)                                                     \
    {                                                                      \
        _Pragma("unroll")                                                  \
        for (int i = 0; i < 4; ++i) {                                      \
            const int R_ = wm * 64 + i * 16 + fr;                          \
            const float* rbase_ = (abuf) + R_ * BK;                        \
            f32x4 lo_ = *(const f32x4*)&rbase_[((2*g4)   ^ (R_ & 7)) * 4]; \
            f32x4 hi_ = *(const f32x4*)&rbase_[((2*g4+1) ^ (R_ & 7)) * 4]; \
            aF[i] = (bf16x8){(__bf16)lo_.x, (__bf16)lo_.y, (__bf16)lo_.z,  \
                             (__bf16)lo_.w, (__bf16)hi_.x, (__bf16)hi_.y,  \
                             (__bf16)hi_.z, (__bf16)hi_.w};                \
        }                                                                  \
    }

    // B frag: RB = wn*128 + (qb+j)*16 + fr; slot g4 ^ ((RB>>1)&3)
#define LOAD_B4(buf, qb, BB)                                               \
    {                                                                      \
        _Pragma("unroll")                                                  \
        for (int j = 0; j < 4; ++j) {                                      \
            const int RB_ = wn * 128 + ((qb) + j) * 16 + fr;               \
            BB[j] = *(const bf16x8*)                                       \
                &sB[buf][RB_ * BK + (g4 ^ ((RB_ >> 1) & 3)) * 8];          \
        }                                                                  \
    }

#define MFMA16(qb, BB)                                                     \
    {                                                                      \
        _Pragma("unroll")                                                  \
        for (int i = 0; i < 4; ++i)                                        \
            _Pragma("unroll")                                              \
            for (int j = 0; j < 4; ++j)                                    \
                acc[i][(qb) + j] =                                         \
                    __builtin_amdgcn_mfma_f32_16x16x32_bf16(               \
                        aF[i], BB[j], acc[i][(qb) + j], 0, 0, 0);          \
    }

    // rotating A buffers: a0 = A(kt), a1 = A(kt+1), a2 = stage target A(kt+2)
    float* a0 = &sAf[0][0];
    float* a1 = &sAf[1][0];
    float* a2 = &sAf[2][0];

    // ---- prologue: A(0)[4], B(0)[4], A(1)[4] ----
    STAGE_A(a0, 0);
    STAGE_B(0, 0);
    STAGE_A(a1, 1);

    for (int kt = 0; kt < NKT; ++kt) {
        const int cur = kt & 1;
        const int nxt = cur ^ 1;

        // ---- P1: A-frags + B q0-3, MFMA qb=0 ----
        FENCE();
        if (kt == NKT - 1) asm volatile("s_waitcnt vmcnt(0)" ::: "memory");
        else               asm volatile("s_waitcnt vmcnt(4)" ::: "memory");
        __builtin_amdgcn_s_barrier();
        FENCE();
        if (s < L_OUT) {        // cold path: zero masked rows (block-uniform)
#pragma unroll
            for (int r = 0; r < 4; ++r)
                if (arow[r] >= s)
                    *(f32x4*)&a0[adst[r]] = (f32x4){0.f, 0.f, 0.f, 0.f};
            __syncthreads();
        }
        LOAD_A32(a0);
        LOAD_B4(cur, 0, bBlo);
        if (kt + 1 < NKT) STAGE_B(nxt, kt + 1);
        __builtin_amdgcn_s_setprio(1);
        MFMA16(0, bBlo);
        __builtin_amdgcn_s_setprio(0);

        // ---- P2: B q4-7, MFMA qb=4 ----
        FENCE();
        __builtin_amdgcn_s_barrier();
        FENCE();
        LOAD_B4(cur, 4, bBhi);
        if (kt + 2 < NKT) STAGE_A(a2, kt + 2);   // a2 last read P1(kt-1)
        __builtin_amdgcn_s_setprio(1);
        MFMA16(4, bBhi);
        __builtin_amdgcn_s_setprio(0);

        // rotate A buffers
        float* ta = a0; a0 = a1; a1 = a2; a2 = ta;
    }

    // ---- epilogue: bias + store ----
    const int row0 = m0 + wm * 64 + (lane >> 4) * 4;
    const int col0 = n0 + wn * 128 + fr;
#pragma unroll
    for (int i = 0; i < 4; ++i)
#pragma unroll
        for (int q = 0; q < 8; ++q)
#pragma unroll
            for (int rr = 0; rr < 4; ++rr)
                out[(size_t)(row0 + i * 16 + rr) * D_OUT + (col0 + q * 16)] =
                    acc[i][q][rr] + bias_v[q];

#undef STAGE_A
#undef STAGE_B
#undef LOAD_A32
#undef LOAD_B4
#undef MFMA16
}

// ---------------------------------------------------------------------------
extern "C" void kernel_launch(void* const* d_in, const int* in_sizes, int n_in,
                              void* d_out, int out_size, void* d_ws, size_t ws_size,
                              hipStream_t stream) {
    const float* x    = (const float*)d_in[0];
    const int*   mask = (const int*)d_in[1];
    const float* W    = (const float*)d_in[2];
    const float* bias = (const float*)d_in[3];
    float*       out  = (float*)d_out;

    __bf16* wsW   = (__bf16*)((char*)d_ws + WS_W_OFF);
    int*    s_arr = (int*)((char*)d_ws + WS_S_OFF);

    prep_kernel<<<dim3(16 + D_OUT), dim3(256), 0, stream>>>(
        mask, W, s_arr, wsW);

    const int grid = (M_DIM / BM) * (D_OUT / BN);  // 128 * 4 = 512
    gemm_kernel<<<dim3(grid), dim3(256), 0, stream>>>(
        x, wsW, bias, s_arr, out);
}